// Round 2
// baseline (134.387 us; speedup 1.0000x reference)
//
#include <hip/hip_runtime.h>

#define S_TOT 37448
#define OUT_T 5704
#define EMB 256

typedef unsigned short u16;
typedef __bf16 bf16x8 __attribute__((ext_vector_type(8)));
typedef float f32x4 __attribute__((ext_vector_type(4)));
typedef unsigned short u16x4 __attribute__((ext_vector_type(4)));
typedef unsigned short u16x8 __attribute__((ext_vector_type(8)));

__device__ __forceinline__ u16 f2bf(float f) {
  union { float f; unsigned int i; } v;
  v.f = f;
  unsigned int x = v.i;
  return (u16)((x + 0x7fffu + ((x >> 16) & 1u)) >> 16);
}

// ---------------- layers 0-2: pure embedding gather (all f32, exact) --------
__global__ __launch_bounds__(256) void emb_small(
    const int* __restrict__ value, const int* __restrict__ depth,
    const int* __restrict__ position,
    const float* __restrict__ ve0, const float* __restrict__ pe0, const float* __restrict__ de0,
    const float* __restrict__ ve1, const float* __restrict__ pe1, const float* __restrict__ de1,
    const float* __restrict__ ve2, const float* __restrict__ pe2, const float* __restrict__ de2,
    float* __restrict__ out) {
  const int tok = blockIdx.x;            // 0 .. 8*584-1
  const int b = tok / 584;
  const int t = tok - b * 584;
  const float *ve, *pe, *de;
  if (t < 8)       { ve = ve0; pe = pe0; de = de0; }
  else if (t < 72) { ve = ve1; pe = pe1; de = de1; }
  else             { ve = ve2; pe = pe2; de = de2; }
  const long base = (long)b * S_TOT + t;
  const int v = value[base];
  const int d = depth[base];
  const int p0 = position[base * 3 + 0];
  const int p1 = position[base * 3 + 1];
  const int p2 = position[base * 3 + 2];
  const int e = threadIdx.x;
  const float sum = ve[v * EMB + e] + pe[p0 * EMB + e] +
                    pe[(64 + p1) * EMB + e] + pe[(128 + p2) * EMB + e] +
                    de[d * EMB + e];
  out[((long)b * OUT_T + t) * EMB + e] = sum;
}

// ------- W repack: f32 (O,E,k) -> bf16 Wt[o][kk*256+e] ----------------------
__global__ __launch_bounds__(256) void transpose_w(
    const float* __restrict__ w3, const float* __restrict__ w4,
    u16* __restrict__ wt3, u16* __restrict__ wt4) {
  const int i = blockIdx.x * 256 + threadIdx.x;
  if (i < 256 * 1024) {
    const int o = i >> 10, c = i & 1023, kk = c >> 8, e = c & 255;
    wt3[i] = f2bf(w3[o * 1024 + e * 4 + kk]);
  }
  if (i < 256 * 2048) {
    const int o = i >> 11, c = i & 2047, kk = c >> 8, e = c & 255;
    wt4[i] = f2bf(w4[o * 2048 + e * 8 + kk]);
  }
}

// ---------------- fused gather + GEMM for conv layers ----------------------
// A: [M=8*T, K]  A[row, kk*256+e] = x[b, to*CK+kk, e]  (gathered, f32 -> bf16)
// B: [K, 256]    B[kk*256+e, o]   = w[o, e, kk]        (from bf16 Wt)
// C: [M, 256] -> out[b, OUT0+to, o] + bias[o]          (f32)
template <int K, int LOG2T, int CK, int S0, int OUT0>
__global__ __launch_bounds__(512) void conv_gemm(
    const int* __restrict__ value, const int* __restrict__ position,
    const float* __restrict__ ve, const float* __restrict__ pe,
    const u16* __restrict__ wt,     // transposed bf16 weights [256][K] (may be null)
    const float* __restrict__ wraw, // original f32 (256,256,CK) fallback
    const float* __restrict__ bias,
    float* __restrict__ out) {
  constexpr int T = 1 << LOG2T;
  constexpr int NS = K / 32;
  constexpr int LDA = 48;  // padded row stride in u16 (96B, 16B-multiple)
  __shared__ __align__(16) u16 As[64 * LDA];
  __shared__ __align__(16) u16 Bs[256 * LDA];

  const int tid = threadIdx.x;
  const int lane = tid & 63;
  const int wid = tid >> 6;
  const int wr = wid >> 2;  // 0..1
  const int wc = wid & 3;   // 0..3
  const int fr = lane & 15;
  const int fq = lane >> 4;  // 0..3
  const int row0 = blockIdx.x * 64;

  // A-staging: 8 threads per row, 4 elems each (covers 64 x 32)
  const int arow = tid >> 3;
  const int acol0 = (tid & 7) * 4;
  const int grow_s = row0 + arow;
  const int b_s = grow_s >> LOG2T;
  const int to_s = grow_s & (T - 1);
  // B-staging: 2 threads per row (o), 16 elems each (covers 256 x 32)
  const int brow = tid >> 1;
  const int bcol0 = (tid & 1) * 16;

  f32x4 acc[2][4];
#pragma unroll
  for (int m = 0; m < 2; ++m)
#pragma unroll
    for (int n = 0; n < 4; ++n) acc[m][n] = (f32x4){0.f, 0.f, 0.f, 0.f};

  for (int s = 0; s < NS; ++s) {
    // ---- stage A (gather + sum in f32, convert to bf16) ----
    {
      const int kk = s >> 3;        // sub-token within conv group
      const int e0 = (s & 7) * 32;  // embed-dim base of this K-step
      const long sidx = (long)b_s * S_TOT + (S0 + to_s * CK + kk);
      const int v = value[sidx];
      const int* pp = position + sidx * 3;
      const int p0 = pp[0], p1 = pp[1], p2 = pp[2];
      const int e = e0 + acol0;
      float4 va = *(const float4*)(ve + v * EMB + e);
      float4 q0 = *(const float4*)(pe + p0 * EMB + e);
      float4 q1 = *(const float4*)(pe + (64 + p1) * EMB + e);
      float4 q2 = *(const float4*)(pe + (128 + p2) * EMB + e);
      u16x4 r;
      r[0] = f2bf(va.x + q0.x + q1.x + q2.x);
      r[1] = f2bf(va.y + q0.y + q1.y + q2.y);
      r[2] = f2bf(va.z + q0.z + q1.z + q2.z);
      r[3] = f2bf(va.w + q0.w + q1.w + q2.w);
      *(u16x4*)(&As[arow * LDA + acol0]) = r;
    }
    // ---- stage B (weights) ----
    if (wt) {
      const u16* src = wt + (long)brow * K + s * 32 + bcol0;
      u16x8 w0 = *(const u16x8*)(src);
      u16x8 w1 = *(const u16x8*)(src + 8);
      *(u16x8*)(&Bs[brow * LDA + bcol0]) = w0;
      *(u16x8*)(&Bs[brow * LDA + bcol0 + 8]) = w1;
    } else {
      const int kk = s >> 3;
      const int e0 = (s & 7) * 32 + bcol0;
#pragma unroll
      for (int j = 0; j < 16; ++j)
        Bs[brow * LDA + bcol0 + j] = f2bf(wraw[brow * (EMB * CK) + (e0 + j) * CK + kk]);
    }
    __syncthreads();
    // ---- MFMA ----
    bf16x8 af[2], bfr[4];
#pragma unroll
    for (int m = 0; m < 2; ++m) {
      u16x8 tmp = *(const u16x8*)(&As[(wr * 32 + m * 16 + fr) * LDA + fq * 8]);
      af[m] = __builtin_bit_cast(bf16x8, tmp);
    }
#pragma unroll
    for (int n = 0; n < 4; ++n) {
      u16x8 tmp = *(const u16x8*)(&Bs[(wc * 64 + n * 16 + fr) * LDA + fq * 8]);
      bfr[n] = __builtin_bit_cast(bf16x8, tmp);
    }
#pragma unroll
    for (int m = 0; m < 2; ++m)
#pragma unroll
      for (int n = 0; n < 4; ++n)
        acc[m][n] = __builtin_amdgcn_mfma_f32_16x16x32_bf16(af[m], bfr[n], acc[m][n], 0, 0, 0);
    __syncthreads();
  }

  // ---- epilogue: bias + f32 store ----
  float bz[4];
#pragma unroll
  for (int n = 0; n < 4; ++n) bz[n] = bias[wc * 64 + n * 16 + fr];
#pragma unroll
  for (int m = 0; m < 2; ++m) {
#pragma unroll
    for (int reg = 0; reg < 4; ++reg) {
      const int grow = row0 + wr * 32 + m * 16 + fq * 4 + reg;
      const int bb = grow >> LOG2T;
      const int to = grow & (T - 1);
      float* op = out + ((long)bb * OUT_T + OUT0 + to) * EMB;
#pragma unroll
      for (int n = 0; n < 4; ++n)
        op[wc * 64 + n * 16 + fr] = acc[m][n][reg] + bz[n];
    }
  }
}

extern "C" void kernel_launch(void* const* d_in, const int* in_sizes, int n_in,
                              void* d_out, int out_size, void* d_ws, size_t ws_size,
                              hipStream_t stream) {
  // dict order: value, depth, position, (val_emb_l, pos_emb_l) l=0..4,
  // dep_emb_0..2, conv_w_3, conv_b_3, conv_w_4, conv_b_4
  const int* value = (const int*)d_in[0];
  const int* depth = (const int*)d_in[1];
  const int* position = (const int*)d_in[2];
  const float* ve0 = (const float*)d_in[3];
  const float* pe0 = (const float*)d_in[4];
  const float* ve1 = (const float*)d_in[5];
  const float* pe1 = (const float*)d_in[6];
  const float* ve2 = (const float*)d_in[7];
  const float* pe2 = (const float*)d_in[8];
  const float* ve3 = (const float*)d_in[9];
  const float* pe3 = (const float*)d_in[10];
  const float* ve4 = (const float*)d_in[11];
  const float* pe4 = (const float*)d_in[12];
  const float* de0 = (const float*)d_in[13];
  const float* de1 = (const float*)d_in[14];
  const float* de2 = (const float*)d_in[15];
  const float* w3 = (const float*)d_in[16];
  const float* b3 = (const float*)d_in[17];
  const float* w4 = (const float*)d_in[18];
  const float* b4 = (const float*)d_in[19];
  float* out = (float*)d_out;

  u16* wt3 = nullptr;
  u16* wt4 = nullptr;
  if (ws_size >= (size_t)(256 * 1024 + 256 * 2048) * sizeof(u16)) {
    wt3 = (u16*)d_ws;
    wt4 = wt3 + 256 * 1024;
    transpose_w<<<(256 * 2048) / 256, 256, 0, stream>>>(w3, w4, wt3, wt4);
  }
  emb_small<<<8 * 584, 256, 0, stream>>>(value, depth, position, ve0, pe0, de0,
                                         ve1, pe1, de1, ve2, pe2, de2, out);
  conv_gemm<1024, 10, 4, 584, 584><<<128, 512, 0, stream>>>(
      value, position, ve3, pe3, wt3, w3, b3, out);
  conv_gemm<2048, 12, 8, 4680, 1608><<<512, 512, 0, stream>>>(
      value, position, ve4, pe4, wt4, w4, b4, out);
}

// Round 3
// 108.628 us; speedup vs baseline: 1.2371x; 1.2371x over previous
//
#include <hip/hip_runtime.h>

#define S_TOT 37448
#define OUT_T 5704
#define EMB 256

typedef unsigned short u16;
typedef __bf16 bf16x8 __attribute__((ext_vector_type(8)));
typedef float f32x4 __attribute__((ext_vector_type(4)));
typedef unsigned short u16x8 __attribute__((ext_vector_type(8)));

__device__ __forceinline__ u16 f2bf(float f) {
  union { float f; unsigned int i; } v;
  v.f = f;
  unsigned int x = v.i;
  return (u16)((x + 0x7fffu + ((x >> 16) & 1u)) >> 16);
}

__device__ __forceinline__ u16x8 pack8(const float4& lo, const float4& hi) {
  u16x8 r;
  r[0] = f2bf(lo.x); r[1] = f2bf(lo.y); r[2] = f2bf(lo.z); r[3] = f2bf(lo.w);
  r[4] = f2bf(hi.x); r[5] = f2bf(hi.y); r[6] = f2bf(hi.z); r[7] = f2bf(hi.w);
  return r;
}

#define GLOAD_LDS16(g, l)                                                     \
  __builtin_amdgcn_global_load_lds((const __attribute__((address_space(1))) void*)(g), \
                                   (__attribute__((address_space(3))) void*)(l), 16, 0, 0)

// ---------------- layers 0-2: pure embedding gather (f32, exact) ------------
__global__ __launch_bounds__(256) void emb_small(
    const int* __restrict__ value, const int* __restrict__ depth,
    const int* __restrict__ position,
    const float* __restrict__ ve0, const float* __restrict__ pe0, const float* __restrict__ de0,
    const float* __restrict__ ve1, const float* __restrict__ pe1, const float* __restrict__ de1,
    const float* __restrict__ ve2, const float* __restrict__ pe2, const float* __restrict__ de2,
    float* __restrict__ out) {
  const int tok = blockIdx.x;
  const int b = tok / 584;
  const int t = tok - b * 584;
  const float *ve, *pe, *de;
  if (t < 8)       { ve = ve0; pe = pe0; de = de0; }
  else if (t < 72) { ve = ve1; pe = pe1; de = de1; }
  else             { ve = ve2; pe = pe2; de = de2; }
  const long base = (long)b * S_TOT + t;
  const int v = value[base];
  const int d = depth[base];
  const int p0 = position[base * 3 + 0];
  const int p1 = position[base * 3 + 1];
  const int p2 = position[base * 3 + 2];
  const int e = threadIdx.x;
  const float sum = ve[v * EMB + e] + pe[p0 * EMB + e] +
                    pe[(64 + p1) * EMB + e] + pe[(128 + p2) * EMB + e] +
                    de[d * EMB + e];
  out[((long)b * OUT_T + t) * EMB + e] = sum;
}

// ------- W repack: f32 (O,E,k) -> bf16 Wt[o][kk*256+e] ----------------------
__global__ __launch_bounds__(256) void transpose_w(
    const float* __restrict__ w3, const float* __restrict__ w4,
    u16* __restrict__ wt3, u16* __restrict__ wt4) {
  const int i = blockIdx.x * 256 + threadIdx.x;
  if (i < 256 * 1024) {
    const int o = i >> 10, c = i & 1023, kk = c >> 8, e = c & 255;
    wt3[i] = f2bf(w3[o * 1024 + e * 4 + kk]);
  }
  if (i < 256 * 2048) {
    const int o = i >> 11, c = i & 2047, kk = c >> 8, e = c & 255;
    wt4[i] = f2bf(w4[o * 2048 + e * 8 + kk]);
  }
}

// ---------------- fused gather + GEMM, pipelined ----------------------------
// BM=64, BN=256, BK=32. 256 threads = 4 waves; wave w owns output cols
// [w*64, w*64+64), all 64 rows: acc[4][4] of 16x16 frags -> 16 MFMA / step.
// LDS tiles are [row][32] u16 with XOR granule swizzle g ^= (row>>1)&3
// (applied on ds_write/global-src AND read -> <=2-way bank access, free).
template <int K, int LOG2T, int CK, int S0, int OUT0>
__device__ __forceinline__ void conv_tile(
    int bid, const int* __restrict__ value, const int* __restrict__ position,
    const float* __restrict__ ve, const float* __restrict__ pe,
    const u16* __restrict__ wt, const float* __restrict__ wraw,
    const float* __restrict__ bias, float* __restrict__ out,
    u16 (*As)[64 * 32], u16 (*Bs)[256 * 32], int4* idxc) {
  constexpr int T = 1 << LOG2T;
  constexpr int NS = K / 32;
  const int tid = threadIdx.x;
  const int lane = tid & 63;
  const int wid = tid >> 6;  // 0..3: output-col group
  const int fr = lane & 15;
  const int fq = lane >> 4;  // 0..3
  const int row0 = bid * 64;

  // ---- prologue: cache all (v,p0,p1,p2) quads for this block's rows ----
  for (int e = tid; e < 64 * CK; e += 256) {
    const int r = e / CK, kk = e % CK;
    const int grow = row0 + r;
    const int b = grow >> LOG2T;
    const int to = grow & (T - 1);
    const long sidx = (long)b * S_TOT + (S0 + to * CK + kk);
    int4 q;
    q.x = value[sidx];
    const int* pp = position + sidx * 3;
    q.y = pp[0]; q.z = pp[1]; q.w = pp[2];
    idxc[e] = q;
  }
  __syncthreads();

  // A-staging geometry: thread covers (row = tid>>2, 8 cols at (tid&3)*8)
  const int arow = tid >> 2;
  const int agc = tid & 3;                       // content granule
  const int aslot = agc ^ ((arow >> 1) & 3);     // swizzled LDS granule
  const int aoff = arow * 32 + aslot * 8;        // elem offset in As[buf]

  // B-staging geometry (global_load_lds): issue j stages rows j*64+wid*16..+16
  const int brl_base = wid * 16 + (lane >> 2);
  const int bslot = lane & 3;

  auto gatherA = [&](int s, float4& lo, float4& hi) {
    const int kk = s >> 3;
    const int e0 = (s & 7) * 32 + agc * 8;
    const int4 q = idxc[arow * CK + kk];
    const float* a0 = ve + q.x * EMB + e0;
    const float* a1 = pe + q.y * EMB + e0;
    const float* a2 = pe + (64 + q.z) * EMB + e0;
    const float* a3 = pe + (128 + q.w) * EMB + e0;
    float4 x0 = *(const float4*)a0, x1 = *(const float4*)(a0 + 4);
    float4 y0 = *(const float4*)a1, y1 = *(const float4*)(a1 + 4);
    float4 z0 = *(const float4*)a2, z1 = *(const float4*)(a2 + 4);
    float4 u0 = *(const float4*)a3, u1 = *(const float4*)(a3 + 4);
    lo.x = x0.x + y0.x + z0.x + u0.x;
    lo.y = x0.y + y0.y + z0.y + u0.y;
    lo.z = x0.z + y0.z + z0.z + u0.z;
    lo.w = x0.w + y0.w + z0.w + u0.w;
    hi.x = x1.x + y1.x + z1.x + u1.x;
    hi.y = x1.y + y1.y + z1.y + u1.y;
    hi.z = x1.z + y1.z + z1.z + u1.z;
    hi.w = x1.w + y1.w + z1.w + u1.w;
  };

  auto issueB = [&](int s, int buf) {
    if (wt) {
#pragma unroll
      for (int j = 0; j < 4; ++j) {
        const int rl = j * 64 + brl_base;
        const int gc = bslot ^ ((rl >> 1) & 3);  // pre-swizzled SOURCE
        const u16* src = wt + (long)rl * K + s * 32 + gc * 8;
        u16* dst = &Bs[buf][(j * 64 + wid * 16) * 32];  // linear dest
        GLOAD_LDS16(src, dst);
      }
    } else {
      const int o = tid;
      const int kk = s >> 3, e0 = (s & 7) * 32;
      const int osw = (o >> 1) & 3;
#pragma unroll
      for (int g = 0; g < 4; ++g) {
        u16x8 r;
#pragma unroll
        for (int c = 0; c < 8; ++c)
          r[c] = f2bf(wraw[(long)o * (EMB * CK) + (e0 + g * 8 + c) * CK + kk]);
        *(u16x8*)(&Bs[buf][o * 32 + (g ^ osw) * 8]) = r;
      }
    }
  };

  f32x4 acc[4][4];
#pragma unroll
  for (int m = 0; m < 4; ++m)
#pragma unroll
    for (int n = 0; n < 4; ++n) acc[m][n] = (f32x4){0.f, 0.f, 0.f, 0.f};

  // prologue stage of step 0
  {
    float4 lo, hi;
    gatherA(0, lo, hi);
    issueB(0, 0);
    *(u16x8*)(&As[0][aoff]) = pack8(lo, hi);
  }
  __syncthreads();

  int cur = 0;
  for (int s = 0; s < NS; ++s) {
    const int nxt = cur ^ 1;
    const bool more = (s + 1 < NS);
    float4 plo, phi;
    if (more) {
      gatherA(s + 1, plo, phi);   // issue table loads (regs)
      issueB(s + 1, nxt);         // issue async B -> LDS buf[nxt]
    }
    bf16x8 af[4], bfv[4];
#pragma unroll
    for (int m = 0; m < 4; ++m) {
      const int r = m * 16 + fr;
      u16x8 t = *(const u16x8*)(&As[cur][r * 32 + (fq ^ ((r >> 1) & 3)) * 8]);
      af[m] = __builtin_bit_cast(bf16x8, t);
    }
#pragma unroll
    for (int n = 0; n < 4; ++n) {
      const int o = wid * 64 + n * 16 + fr;
      u16x8 t = *(const u16x8*)(&Bs[cur][o * 32 + (fq ^ ((o >> 1) & 3)) * 8]);
      bfv[n] = __builtin_bit_cast(bf16x8, t);
    }
#pragma unroll
    for (int m = 0; m < 4; ++m)
#pragma unroll
      for (int n = 0; n < 4; ++n)
        acc[m][n] = __builtin_amdgcn_mfma_f32_16x16x32_bf16(af[m], bfv[n], acc[m][n], 0, 0, 0);
    if (more) *(u16x8*)(&As[nxt][aoff]) = pack8(plo, phi);
    __syncthreads();
    cur = nxt;
  }

  // ---- epilogue: bias + f32 store ----
  float bz[4];
#pragma unroll
  for (int n = 0; n < 4; ++n) bz[n] = bias[wid * 64 + n * 16 + fr];
#pragma unroll
  for (int m = 0; m < 4; ++m) {
#pragma unroll
    for (int reg = 0; reg < 4; ++reg) {
      const int grow = row0 + m * 16 + fq * 4 + reg;
      const int bb = grow >> LOG2T;
      const int to = grow & (T - 1);
      float* op = out + ((long)bb * OUT_T + OUT0 + to) * EMB + wid * 64 + fr;
#pragma unroll
      for (int n = 0; n < 4; ++n) op[n * 16] = acc[m][n][reg] + bz[n];
    }
  }
}

__global__ __launch_bounds__(256) void conv_fused(
    const int* __restrict__ value, const int* __restrict__ position,
    const float* __restrict__ ve3, const float* __restrict__ pe3,
    const u16* __restrict__ wt3, const float* __restrict__ w3, const float* __restrict__ b3,
    const float* __restrict__ ve4, const float* __restrict__ pe4,
    const u16* __restrict__ wt4, const float* __restrict__ w4, const float* __restrict__ b4,
    float* __restrict__ out) {
  __shared__ __align__(16) u16 As[2][64 * 32];
  __shared__ __align__(16) u16 Bs[2][256 * 32];
  __shared__ __align__(16) int4 idxc[64 * 8];
  if (blockIdx.x < 128)
    conv_tile<1024, 10, 4, 584, 584>(blockIdx.x, value, position, ve3, pe3,
                                     wt3, w3, b3, out, As, Bs, idxc);
  else
    conv_tile<2048, 12, 8, 4680, 1608>(blockIdx.x - 128, value, position, ve4,
                                       pe4, wt4, w4, b4, out, As, Bs, idxc);
}

extern "C" void kernel_launch(void* const* d_in, const int* in_sizes, int n_in,
                              void* d_out, int out_size, void* d_ws, size_t ws_size,
                              hipStream_t stream) {
  const int* value = (const int*)d_in[0];
  const int* position = (const int*)d_in[2];
  const int* depth = (const int*)d_in[1];
  const float* ve0 = (const float*)d_in[3];
  const float* pe0 = (const float*)d_in[4];
  const float* ve1 = (const float*)d_in[5];
  const float* pe1 = (const float*)d_in[6];
  const float* ve2 = (const float*)d_in[7];
  const float* pe2 = (const float*)d_in[8];
  const float* ve3 = (const float*)d_in[9];
  const float* pe3 = (const float*)d_in[10];
  const float* ve4 = (const float*)d_in[11];
  const float* pe4 = (const float*)d_in[12];
  const float* de0 = (const float*)d_in[13];
  const float* de1 = (const float*)d_in[14];
  const float* de2 = (const float*)d_in[15];
  const float* w3 = (const float*)d_in[16];
  const float* b3 = (const float*)d_in[17];
  const float* w4 = (const float*)d_in[18];
  const float* b4 = (const float*)d_in[19];
  float* out = (float*)d_out;

  u16* wt3 = nullptr;
  u16* wt4 = nullptr;
  if (ws_size >= (size_t)(256 * 1024 + 256 * 2048) * sizeof(u16)) {
    wt3 = (u16*)d_ws;
    wt4 = wt3 + 256 * 1024;
    transpose_w<<<(256 * 2048) / 256, 256, 0, stream>>>(w3, w4, wt3, wt4);
  }
  emb_small<<<8 * 584, 256, 0, stream>>>(value, depth, position, ve0, pe0, de0,
                                         ve1, pe1, de1, ve2, pe2, de2, out);
  conv_fused<<<128 + 512, 256, 0, stream>>>(value, position, ve3, pe3, wt3, w3,
                                            b3, ve4, pe4, wt4, w4, b4, out);
}